// Round 16
// baseline (57.434 us; speedup 1.0000x reference)
//
#include <hip/hip_runtime.h>
#include <hip/hip_bf16.h>

namespace {
constexpr int NG  = 4096;   // grid points per batch
constexpr int NTt = 4096;   // target points
constexpr int DZc = 128;
constexpr int NKc = 2;
constexpr int GT  = 32;     // g per chunk (one MFMA-K)
constexpr int NCH = NG / GT;                              // 128 chunks per b
constexpr long CHUNK_B   = (long)DZc * GT * 2;            // 8192 B per chunk
constexpr long IMG_BYTES = 4L * NCH * CHUNK_B;            // 4.19 MB

typedef __attribute__((ext_vector_type(8))) short bf16x8;
typedef __attribute__((ext_vector_type(4))) float f32x4;
typedef __attribute__((ext_vector_type(4))) unsigned int uintx4;

template <bool B> struct BoolC { static constexpr bool value = B; };

__device__ __forceinline__ short f2bf(float x) {
    __hip_bfloat16 h = __float2bfloat16(x);
    return __builtin_bit_cast(short, h);
}

__device__ __forceinline__ unsigned fbits(float x) {
    return __builtin_bit_cast(unsigned, x);
}

// pack hi16(we) | hi16(wo)<<16 : elem0 = we (bf16 RTZ), elem1 = wo
__device__ __forceinline__ unsigned pk_bf16(float we, float wo) {
    return __builtin_amdgcn_perm(fbits(wo), fbits(we), 0x07060302u);
}

__device__ __forceinline__ void gload16(const void* g, void* lds) {
    __builtin_amdgcn_global_load_lds(
        (const __attribute__((address_space(1))) void*)g,
        (__attribute__((address_space(3))) void*)lds, 16, 0, 0);
}
}

// ---------------------------------------------------------------------------
// Pre-kernel: z fp32 [b][g][128] -> bf16 chunk images (8 KB / 32 g) in ws.
// Chunk c physical 16B-block p: d = p>>2, ps = p&3. Logical slot
// s = ps ^ ((d>>1)&3), g = c*32 + s*8 + j, value = bf16(z[b][g][d]).
// ---------------------------------------------------------------------------
__global__ __launch_bounds__(256)
void zcvt_kernel(const float* __restrict__ zg, short* __restrict__ img)
{
    __shared__ __align__(16) float tile[GT * 132];   // [s][d] fp32, row pad->132
    const int tid = threadIdx.x;
    const int blk = blockIdx.x;        // 512 = 4 b x 128 c
    const int c = blk & 127, b = blk >> 7;
    const float* zb = zg + ((long)(b * NG + c * GT)) * DZc;
#pragma unroll
    for (int it = 0; it < 4; ++it) {
        int f = tid + it * 256;        // 1024 float4 tiles
        int s = f >> 5, dq = f & 31;
        float4 v = *(const float4*)(zb + (long)s * DZc + dq * 4);
        *(float4*)&tile[s * 132 + dq * 4] = v;
    }
    __syncthreads();
    char* ib = (char*)img + (long)blk * CHUNK_B;
#pragma unroll
    for (int it = 0; it < 2; ++it) {
        int p = tid + it * 256;        // 16B block id 0..511
        int y = p * 16;
        int d  = p >> 2;
        int ps = p & 3;
        int s8 = (ps ^ ((d >> 1) & 3)) * 8;
        bf16x8 o;
#pragma unroll
        for (int j = 0; j < 8; ++j) o[j] = f2bf(tile[(s8 + j) * 132 + d]);
        *(bf16x8*)(ib + y) = o;
    }
}

// ---------------------------------------------------------------------------
// Main kernel: 256 blocks (b, 64t-tile) x 512 threads = 8 waves (4wt x 2ws).
// Wave (wt, ws): 16t x FULL 128d, K-half ws (64 chunks, 32 iters x 2 chunks).
// R15's 2-chunk barrier windows + R13's 2 blocks/CU (64 KB LDS): barrier
// stalls of one block overlap the other block's compute on the same CU.
// LDS: 2 regions x 2 dbuf x 16 KB = 64 KB. Split-K=2 halves the epilogue.
// ---------------------------------------------------------------------------
__global__ __launch_bounds__(512, 4)
void setconv_main(const float* __restrict__ xgrid, const float* __restrict__ xt,
                  const float* __restrict__ lsp, const short* __restrict__ zimg,
                  float* __restrict__ out)
{
    __shared__ __align__(16) char lds[65536];

    const int tid  = threadIdx.x;
    const int lane = tid & 63;
    const int wid  = tid >> 6;
    const int wt = wid >> 1;          // 0..3 t-stripe
    const int ws = wid & 1;           // K-half
    const int hi = lane >> 4;
    const int lm = lane & 15;

    // XCD swizzle: 32 consecutive lb per XCD
    const int lb = ((blockIdx.x & 7) << 5) | (blockIdx.x >> 3);
    const int b  = lb >> 6;
    const int t0 = (lb & 63) << 6;

    float a00, a01, a10, a11;
    {
        const float LOG2E = 1.4426950408889634f;
        float cf[2][2];
#pragma unroll
        for (int d = 0; d < 2; ++d)
#pragma unroll
            for (int k = 0; k < 2; ++k) {
                float p  = lsp[d * 2 + k];
                float sp = fmaxf(p, 0.0f) + log1pf(__expf(-fabsf(p)));
                float ls = 1e-5f + sp;
                cf[d][k] = -0.5f * LOG2E / (ls * ls);
            }
        a00 = cf[0][0]; a01 = cf[0][1]; a10 = cf[1][0]; a11 = cf[1][1];
    }
    // RTZ-centering bias: truncation err [0,2^-8) -> scale by (1+2^-9)
    const float CB = 0.002818906f;    // log2(1 + 2^-9)

    const int t = t0 + wt * 16 + lm;
    const float2 xtv = *(const float2*)&xt[((long)b * NTt + t) * 2];

    f32x4 acc[8][2];
#pragma unroll
    for (int db = 0; db < 8; ++db)
#pragma unroll
        for (int k = 0; k < 2; ++k) acc[db][k] = (f32x4){0.f, 0.f, 0.f, 0.f};

    const char* imgb = (const char*)zimg + (long)b * NCH * CHUNK_B;
    const float* xgb = xgrid + (long)b * NG * 2;

    // per-lane swizzled read base within a chunk
    const int roff = lm * 64 + ((hi ^ ((lm >> 1) & 3)) << 4);

    // uniform fast path: lengthscale tiled over dx => a00==a10, a01==a11
    const bool eq = (a00 == a10) && (a01 == a11);

    auto run = [&](auto eqc) {
        constexpr bool EQv = decltype(eqc)::value;
        float4 xgN[4];     // xg prefetch for the NEXT sub-chunk

        // stage 2 chunks (i2, i2+1) per region into buffer buf: 32 KB total,
        // 512 threads x 4 gload16. v = u*512+tid: r=v>>10, h=(v>>9)&1,
        // o=(v&511)*16 = tid*16  (r,h wave-uniform; dest = base + lane*16).
        auto stage = [&](int i2, int buf) {
#pragma unroll
            for (int u = 0; u < 4; ++u) {
                const int v = u * 512 + tid;
                const int r = v >> 10;
                const int h = (v >> 9) & 1;
                const int o = (v & 511) * 16;
                const char* src = imgb + ((long)(r * 64 + i2 + h)) * CHUNK_B + o;
                char* dst = lds + r * 32768 + buf * 16384 + h * 8192 + o;
                gload16(src, dst);
            }
        };
        auto loadxg = [&](int c) {
            const float4* p = (const float4*)(xgb + (c * GT + hi * 8) * 2);
            xgN[0] = p[0]; xgN[1] = p[1]; xgN[2] = p[2]; xgN[3] = p[3];
        };

        stage(0, 0);
        loadxg(ws * 64);
        __syncthreads();

        for (int i = 0; i < 32; ++i) {
            const int buf = i & 1;
            if (i + 1 < 32) stage(2 * (i + 1), buf ^ 1);

#pragma unroll
            for (int h = 0; h < 2; ++h) {
                const int c = ws * 64 + 2 * i + h;
                const char* rb = lds + ws * 32768 + buf * 16384 + h * 8192 + roff;

                // ---- A-gen from prefetched xgN (EQ path; v_perm_b32 packing)
                unsigned u0[4], u1[4];
#pragma unroll
                for (int jp = 0; jp < 4; ++jp) {
                    float4 q = xgN[jp];
                    float dx0 = xtv.x - q.x, dy0 = xtv.y - q.y;
                    float dx1 = xtv.x - q.z, dy1 = xtv.y - q.w;
                    float w00, w01, w10, w11;
                    if constexpr (EQv) {
                        float s0 = fmaf(dy0, dy0, dx0 * dx0);
                        float s1 = fmaf(dy1, dy1, dx1 * dx1);
                        w00 = __builtin_amdgcn_exp2f(fmaf(s0, a00, CB));
                        w10 = __builtin_amdgcn_exp2f(fmaf(s0, a01, CB));
                        w01 = __builtin_amdgcn_exp2f(fmaf(s1, a00, CB));
                        w11 = __builtin_amdgcn_exp2f(fmaf(s1, a01, CB));
                    } else {
                        float sx0 = dx0 * dx0, sy0 = dy0 * dy0;
                        float sx1 = dx1 * dx1, sy1 = dy1 * dy1;
                        w00 = __builtin_amdgcn_exp2f(fmaf(sy0, a10, fmaf(sx0, a00, CB)));
                        w10 = __builtin_amdgcn_exp2f(fmaf(sy0, a11, fmaf(sx0, a01, CB)));
                        w01 = __builtin_amdgcn_exp2f(fmaf(sy1, a10, fmaf(sx1, a00, CB)));
                        w11 = __builtin_amdgcn_exp2f(fmaf(sy1, a11, fmaf(sx1, a01, CB)));
                    }
                    u0[jp] = pk_bf16(w00, w01);
                    u1[jp] = pk_bf16(w10, w11);
                }
                bf16x8 A0 = __builtin_bit_cast(bf16x8, (uintx4){u0[0], u0[1], u0[2], u0[3]});
                bf16x8 A1 = __builtin_bit_cast(bf16x8, (uintx4){u1[0], u1[1], u1[2], u1[3]});

                if (c + 1 < ws * 64 + 64) loadxg(c + 1);

#pragma unroll
                for (int db = 0; db < 8; ++db) {
                    bf16x8 Bf = *(const bf16x8*)(rb + db * 1024);
                    acc[db][0] = __builtin_amdgcn_mfma_f32_16x16x32_bf16(A0, Bf, acc[db][0], 0, 0, 0);
                    acc[db][1] = __builtin_amdgcn_mfma_f32_16x16x32_bf16(A1, Bf, acc[db][1], 0, 0, 0);
                }
            }
            __syncthreads();
        }
    };
    if (eq) run(BoolC<true>{}); else run(BoolC<false>{});

    // -------- split-K=2 reduction: db-pair rounds (4 KB slices x 4 wt) ----
    // Round q: db {2q,2q+1}; ws==1 writes slot wt, ws==0 adds + stores.
    float2* area = (float2*)lds;
#pragma unroll
    for (int q = 0; q < 4; ++q) {
        const int d0 = 2 * q;
        if (ws == 1) {
#pragma unroll
            for (int e = 0; e < 2; ++e)
#pragma unroll
                for (int r = 0; r < 4; ++r) {
                    const int row = hi * 4 + r;
                    area[wt * 512 + (e * 16 + row) * 16 + lm] =
                        (float2){acc[d0 + e][0][r], acc[d0 + e][1][r]};
                }
        }
        __syncthreads();
        if (ws == 0) {
#pragma unroll
            for (int e = 0; e < 2; ++e) {
                const int d = (d0 + e) * 16 + lm;
#pragma unroll
                for (int r = 0; r < 4; ++r) {
                    const int row = hi * 4 + r;
                    float2 v = area[wt * 512 + (e * 16 + row) * 16 + lm];
                    const int tt = t0 + wt * 16 + row;
                    *(float2*)&out[(((long)b * NTt + tt) * DZc + d) * NKc] =
                        (float2){acc[d0 + e][0][r] + v.x, acc[d0 + e][1][r] + v.y};
                }
            }
        }
        __syncthreads();
    }
}

// ---------------------------------------------------------------------------
// Fallback (R1 kernel, known good) if ws is too small.
// ---------------------------------------------------------------------------
__global__ __launch_bounds__(256, 1)
void setconv_fused(const float* __restrict__ xgrid, const float* __restrict__ zgrid,
                   const float* __restrict__ xt, const float* __restrict__ lsp,
                   float* __restrict__ out)
{
    __shared__ __align__(16) short zt[2][DZc * 32];
    __shared__ __align__(16) float xgf[2][32 * 2];

    const int tid  = threadIdx.x;
    const int lane = tid & 63;
    const int wid  = tid >> 6;
    const int wt = wid >> 1;
    const int wd = wid & 1;
    const int hi = lane >> 4;
    const int lm = lane & 15;

    const int lb = ((blockIdx.x & 7) << 5) | (blockIdx.x >> 3);
    const int b  = lb >> 6;
    const int t0 = (lb & 63) << 6;

    float a00, a01, a10, a11;
    {
        const float LOG2E = 1.4426950408889634f;
        float cf[2][2];
#pragma unroll
        for (int d = 0; d < 2; ++d)
#pragma unroll
            for (int k = 0; k < 2; ++k) {
                float p  = lsp[d * 2 + k];
                float sp = fmaxf(p, 0.0f) + log1pf(__expf(-fabsf(p)));
                float ls = 1e-5f + sp;
                cf[d][k] = -0.5f * LOG2E / (ls * ls);
            }
        a00 = cf[0][0]; a01 = cf[0][1]; a10 = cf[1][0]; a11 = cf[1][1];
    }

    float xtx[2], xty[2];
#pragma unroll
    for (int ts = 0; ts < 2; ++ts) {
        int t = t0 + wt * 32 + ts * 16 + lm;
        const float* p = &xt[((long)b * NTt + t) * 2];
        xtx[ts] = p[0]; xty[ts] = p[1];
    }

    f32x4 acc[2][4][2];
#pragma unroll
    for (int ts = 0; ts < 2; ++ts)
#pragma unroll
        for (int db = 0; db < 4; ++db)
#pragma unroll
            for (int k = 0; k < 2; ++k)
                acc[ts][db][k] = (f32x4){0.f, 0.f, 0.f, 0.f};

    const int dcol = tid & 127;
    const int g8a  = tid >> 7;
    const long zbase = (long)b * NG * DZc;
    const int swz = (dcol >> 1) & 3;
    const int soff0 = dcol * 32 + ((g8a       ^ swz) * 8);
    const int soff1 = dcol * 32 + (((g8a + 2) ^ swz) * 8);

    float zv[16];
    float xgv = 0.f;

    auto stage_load = [&](int c) {
        const int g0 = c * 32;
        const float* zc0 = zgrid + zbase + (long)(g0 + g8a * 8) * DZc + dcol;
        const float* zc1 = zgrid + zbase + (long)(g0 + (g8a + 2) * 8) * DZc + dcol;
#pragma unroll
        for (int j = 0; j < 8; ++j) zv[j] = zc0[j * DZc];
#pragma unroll
        for (int j = 0; j < 8; ++j) zv[8 + j] = zc1[j * DZc];
        if (wid == 0) xgv = xgrid[((long)b * NG + g0) * 2 + tid];
    };

    auto stage_store = [&](int buf) {
        bf16x8 p0, p1;
#pragma unroll
        for (int j = 0; j < 8; ++j) { p0[j] = f2bf(zv[j]); p1[j] = f2bf(zv[8 + j]); }
        *(bf16x8*)&zt[buf][soff0] = p0;
        *(bf16x8*)&zt[buf][soff1] = p1;
        if (wid == 0) xgf[buf][tid] = xgv;
    };

    auto compute = [&](int buf) {
        typedef __attribute__((ext_vector_type(4))) short short4v;
        bf16x8 Bf[4];
#pragma unroll
        for (int db = 0; db < 4; ++db) {
            const int d = wd * 64 + db * 16 + lm;
            const short* zb = &zt[buf][d * 32];
            const int q = hi ^ (lm & 6);
            short4v lo = *(const short4v*)(zb + q * 4);
            short4v hh = *(const short4v*)(zb + (q ^ 4) * 4);
            Bf[db] = (bf16x8){lo.x, lo.y, lo.z, lo.w, hh.x, hh.y, hh.z, hh.w};
        }
        const float4* xp  = (const float4*)&xgf[buf][hi * 8];
        const float4* xp2 = (const float4*)&xgf[buf][32 + hi * 8];
        float4 x01 = xp[0],  x23 = xp[1];
        float4 x45 = xp2[0], x67 = xp2[1];
        float gx[8] = {x01.x, x01.z, x23.x, x23.z, x45.x, x45.z, x67.x, x67.z};
        float gy[8] = {x01.y, x01.w, x23.y, x23.w, x45.y, x45.w, x67.y, x67.w};
#pragma unroll
        for (int ts = 0; ts < 2; ++ts) {
            bf16x8 A0, A1;
#pragma unroll
            for (int j = 0; j < 8; ++j) {
                float dx = xtx[ts] - gx[j];
                float dy = xty[ts] - gy[j];
                float s0 = dx * dx, s1 = dy * dy;
                A0[j] = f2bf(__builtin_amdgcn_exp2f(s0 * a00 + s1 * a10));
                A1[j] = f2bf(__builtin_amdgcn_exp2f(s0 * a01 + s1 * a11));
            }
#pragma unroll
            for (int db = 0; db < 4; ++db) {
                acc[ts][db][0] = __builtin_amdgcn_mfma_f32_16x16x32_bf16(A0, Bf[db], acc[ts][db][0], 0, 0, 0);
                acc[ts][db][1] = __builtin_amdgcn_mfma_f32_16x16x32_bf16(A1, Bf[db], acc[ts][db][1], 0, 0, 0);
            }
        }
    };

    stage_load(0);
    stage_store(0);
    __syncthreads();

    for (int c = 0; c < NG / 32; ++c) {
        const int cur = c & 1;
        const int nxt = cur ^ 1;
        if (c + 1 < NG / 32) stage_load(c + 1);
        compute(cur);
        if (c + 1 < NG / 32) stage_store(nxt);
        __syncthreads();
    }

#pragma unroll
    for (int ts = 0; ts < 2; ++ts)
#pragma unroll
        for (int db = 0; db < 4; ++db) {
            const int d = wd * 64 + db * 16 + lm;
#pragma unroll
            for (int r = 0; r < 4; ++r) {
                const int t = t0 + wt * 32 + ts * 16 + hi * 4 + r;
                float2 v = {acc[ts][db][0][r], acc[ts][db][1][r]};
                *(float2*)&out[((long)(b * NTt + t) * DZc + d) * NKc] = v;
            }
        }
}

extern "C" void kernel_launch(void* const* d_in, const int* in_sizes, int n_in,
                              void* d_out, int out_size, void* d_ws, size_t ws_size,
                              hipStream_t stream) {
    const float* xg  = (const float*)d_in[0];   // x_grid [4,64,64,2]
    const float* zg  = (const float*)d_in[1];   // z_grid [4,64,64,128]
    const float* xtp = (const float*)d_in[2];   // xt     [4,4096,2]
    const float* ls  = (const float*)d_in[3];   // lengthscale_param [2,2]
    float* o = (float*)d_out;                   // [4,4096,256] fp32

    if (ws_size >= (size_t)IMG_BYTES) {
        short* img = (short*)d_ws;
        hipLaunchKernelGGL(zcvt_kernel, dim3(512), dim3(256), 0, stream, zg, img);
        hipLaunchKernelGGL(setconv_main, dim3(256), dim3(512), 0, stream, xg, xtp, ls, img, o);
    } else {
        hipLaunchKernelGGL(setconv_fused, dim3(256), dim3(256), 0, stream, xg, zg, xtp, ls, o);
    }
}

// Round 17
// 56.857 us; speedup vs baseline: 1.0102x; 1.0102x over previous
//
#include <hip/hip_runtime.h>
#include <hip/hip_bf16.h>

namespace {
constexpr int NG  = 4096;   // grid points per batch
constexpr int NTt = 4096;   // target points
constexpr int DZc = 128;
constexpr int NKc = 2;
constexpr int GT  = 32;     // g per chunk (one MFMA-K)
constexpr int NCH = NG / GT;                              // 128 chunks per b
constexpr long CHUNK_B   = (long)DZc * GT * 2;            // 8192 B per chunk
constexpr long IMG_BYTES = 4L * NCH * CHUNK_B;            // 4.19 MB

typedef __attribute__((ext_vector_type(8))) short bf16x8;
typedef __attribute__((ext_vector_type(4))) float f32x4;
typedef __attribute__((ext_vector_type(4))) unsigned int uintx4;

template <bool B> struct BoolC { static constexpr bool value = B; };

__device__ __forceinline__ short f2bf(float x) {
    __hip_bfloat16 h = __float2bfloat16(x);
    return __builtin_bit_cast(short, h);
}

__device__ __forceinline__ unsigned fbits(float x) {
    return __builtin_bit_cast(unsigned, x);
}

// pack hi16(we) | hi16(wo)<<16 : elem0 = we (bf16 RTZ), elem1 = wo
__device__ __forceinline__ unsigned pk_bf16(float we, float wo) {
    return __builtin_amdgcn_perm(fbits(wo), fbits(we), 0x07060302u);
}

__device__ __forceinline__ void gload16(const void* g, void* lds) {
    __builtin_amdgcn_global_load_lds(
        (const __attribute__((address_space(1))) void*)g,
        (__attribute__((address_space(3))) void*)lds, 16, 0, 0);
}
}

// ---------------------------------------------------------------------------
// Pre-kernel: z fp32 [b][g][128] -> bf16 chunk images (8 KB / 32 g) in ws.
// Chunk c physical 16B-block p: d = p>>2, ps = p&3. Logical slot
// s = ps ^ ((d>>1)&3), g = c*32 + s*8 + j, value = bf16(z[b][g][d]).
// ---------------------------------------------------------------------------
__global__ __launch_bounds__(256)
void zcvt_kernel(const float* __restrict__ zg, short* __restrict__ img)
{
    __shared__ __align__(16) float tile[GT * 132];   // [s][d] fp32, row pad->132
    const int tid = threadIdx.x;
    const int blk = blockIdx.x;        // 512 = 4 b x 128 c
    const int c = blk & 127, b = blk >> 7;
    const float* zb = zg + ((long)(b * NG + c * GT)) * DZc;
#pragma unroll
    for (int it = 0; it < 4; ++it) {
        int f = tid + it * 256;        // 1024 float4 tiles
        int s = f >> 5, dq = f & 31;
        float4 v = *(const float4*)(zb + (long)s * DZc + dq * 4);
        *(float4*)&tile[s * 132 + dq * 4] = v;
    }
    __syncthreads();
    char* ib = (char*)img + (long)blk * CHUNK_B;
#pragma unroll
    for (int it = 0; it < 2; ++it) {
        int p = tid + it * 256;        // 16B block id 0..511
        int y = p * 16;
        int d  = p >> 2;
        int ps = p & 3;
        int s8 = (ps ^ ((d >> 1) & 3)) * 8;
        bf16x8 o;
#pragma unroll
        for (int j = 0; j < 8; ++j) o[j] = f2bf(tile[(s8 + j) * 132 + d]);
        *(bf16x8*)(ib + y) = o;
    }
}

// ---------------------------------------------------------------------------
// Main kernel (R15-verbatim, best known 56.9us): 256 blocks (b, 64t-tile) x
// 1024 threads = 16 waves (4wt x 4ws). Wave (wt, ws): 16t x FULL 128d,
// K-quarter ws. TWO chunks per barrier window:
// 16 iters x {stage 2i+2,2i+3 | compute 2i | compute 2i+1 | barrier}.
// LDS: 4 regions x 2 dbuf x 16 KB = 128 KB -> 1 block/CU, 4 waves/SIMD.
// ---------------------------------------------------------------------------
__global__ __launch_bounds__(1024, 4)
void setconv_main(const float* __restrict__ xgrid, const float* __restrict__ xt,
                  const float* __restrict__ lsp, const short* __restrict__ zimg,
                  float* __restrict__ out)
{
    __shared__ __align__(16) char lds[131072];

    const int tid  = threadIdx.x;
    const int lane = tid & 63;
    const int wid  = tid >> 6;
    const int wt = wid >> 2;          // 0..3 t-stripe
    const int ws = wid & 3;           // K-quarter
    const int hi = lane >> 4;
    const int lm = lane & 15;

    // XCD swizzle: 32 consecutive lb per XCD
    const int lb = ((blockIdx.x & 7) << 5) | (blockIdx.x >> 3);
    const int b  = lb >> 6;
    const int t0 = (lb & 63) << 6;

    float a00, a01, a10, a11;
    {
        const float LOG2E = 1.4426950408889634f;
        float cf[2][2];
#pragma unroll
        for (int d = 0; d < 2; ++d)
#pragma unroll
            for (int k = 0; k < 2; ++k) {
                float p  = lsp[d * 2 + k];
                float sp = fmaxf(p, 0.0f) + log1pf(__expf(-fabsf(p)));
                float ls = 1e-5f + sp;
                cf[d][k] = -0.5f * LOG2E / (ls * ls);
            }
        a00 = cf[0][0]; a01 = cf[0][1]; a10 = cf[1][0]; a11 = cf[1][1];
    }
    // RTZ-centering bias: truncation err [0,2^-8) -> scale by (1+2^-9)
    const float CB = 0.002818906f;    // log2(1 + 2^-9)

    const int t = t0 + wt * 16 + lm;
    const float2 xtv = *(const float2*)&xt[((long)b * NTt + t) * 2];

    f32x4 acc[8][2];
#pragma unroll
    for (int db = 0; db < 8; ++db)
#pragma unroll
        for (int k = 0; k < 2; ++k) acc[db][k] = (f32x4){0.f, 0.f, 0.f, 0.f};

    const char* imgb = (const char*)zimg + (long)b * NCH * CHUNK_B;
    const float* xgb = xgrid + (long)b * NG * 2;

    // per-lane swizzled read base within a chunk
    const int roff = lm * 64 + ((hi ^ ((lm >> 1) & 3)) << 4);

    // uniform fast path: lengthscale tiled over dx => a00==a10, a01==a11
    const bool eq = (a00 == a10) && (a01 == a11);

    auto run = [&](auto eqc) {
        constexpr bool EQv = decltype(eqc)::value;
        float4 xgN[4];     // xg prefetch for the NEXT sub-chunk

        // stage 2 chunks (2i, 2i+1) per region into buffer buf: 64 KB total,
        // 1024 threads x 4 gload16. v = u*1024+tid: r=v>>10, h=(v&1023)>>9,
        // o=(v&511)*16  (r,h wave-uniform; o = base + lane*16).
        auto stage = [&](int i2, int buf) {
#pragma unroll
            for (int u = 0; u < 4; ++u) {
                const int v = u * 1024 + tid;
                const int r = v >> 10;
                const int h = (v >> 9) & 1;
                const int o = (v & 511) * 16;
                const char* src = imgb + ((long)(r * 32 + i2 + h)) * CHUNK_B + o;
                char* dst = lds + r * 32768 + buf * 16384 + h * 8192 + o;
                gload16(src, dst);
            }
        };
        auto loadxg = [&](int c) {
            const float4* p = (const float4*)(xgb + (c * GT + hi * 8) * 2);
            xgN[0] = p[0]; xgN[1] = p[1]; xgN[2] = p[2]; xgN[3] = p[3];
        };

        stage(0, 0);
        loadxg(ws * 32);
        __syncthreads();

        for (int i = 0; i < 16; ++i) {
            const int buf = i & 1;
            if (i + 1 < 16) stage(2 * (i + 1), buf ^ 1);

#pragma unroll
            for (int h = 0; h < 2; ++h) {
                const int c = ws * 32 + 2 * i + h;
                const char* rb = lds + ws * 32768 + buf * 16384 + h * 8192 + roff;

                // ---- A-gen from prefetched xgN (EQ path; v_perm_b32 packing)
                unsigned u0[4], u1[4];
#pragma unroll
                for (int jp = 0; jp < 4; ++jp) {
                    float4 q = xgN[jp];
                    float dx0 = xtv.x - q.x, dy0 = xtv.y - q.y;
                    float dx1 = xtv.x - q.z, dy1 = xtv.y - q.w;
                    float w00, w01, w10, w11;
                    if constexpr (EQv) {
                        float s0 = fmaf(dy0, dy0, dx0 * dx0);
                        float s1 = fmaf(dy1, dy1, dx1 * dx1);
                        w00 = __builtin_amdgcn_exp2f(fmaf(s0, a00, CB));
                        w10 = __builtin_amdgcn_exp2f(fmaf(s0, a01, CB));
                        w01 = __builtin_amdgcn_exp2f(fmaf(s1, a00, CB));
                        w11 = __builtin_amdgcn_exp2f(fmaf(s1, a01, CB));
                    } else {
                        float sx0 = dx0 * dx0, sy0 = dy0 * dy0;
                        float sx1 = dx1 * dx1, sy1 = dy1 * dy1;
                        w00 = __builtin_amdgcn_exp2f(fmaf(sy0, a10, fmaf(sx0, a00, CB)));
                        w10 = __builtin_amdgcn_exp2f(fmaf(sy0, a11, fmaf(sx0, a01, CB)));
                        w01 = __builtin_amdgcn_exp2f(fmaf(sy1, a10, fmaf(sx1, a00, CB)));
                        w11 = __builtin_amdgcn_exp2f(fmaf(sy1, a11, fmaf(sx1, a01, CB)));
                    }
                    u0[jp] = pk_bf16(w00, w01);
                    u1[jp] = pk_bf16(w10, w11);
                }
                bf16x8 A0 = __builtin_bit_cast(bf16x8, (uintx4){u0[0], u0[1], u0[2], u0[3]});
                bf16x8 A1 = __builtin_bit_cast(bf16x8, (uintx4){u1[0], u1[1], u1[2], u1[3]});

                if (c + 1 < ws * 32 + 32) loadxg(c + 1);

#pragma unroll
                for (int db = 0; db < 8; ++db) {
                    bf16x8 Bf = *(const bf16x8*)(rb + db * 1024);
                    acc[db][0] = __builtin_amdgcn_mfma_f32_16x16x32_bf16(A0, Bf, acc[db][0], 0, 0, 0);
                    acc[db][1] = __builtin_amdgcn_mfma_f32_16x16x32_bf16(A1, Bf, acc[db][1], 0, 0, 0);
                }
            }
            __syncthreads();
        }
    };
    if (eq) run(BoolC<true>{}); else run(BoolC<false>{});

    // -------- split-K tree reduction: db-pair rounds (4 KB slices) --------
    // Round q: db {2q,2q+1}; slice = 2db x 16row x 16lm float2 = 4 KB.
    // Phase A: ws 1,3 -> slots wt*2+(ws>>1) (8 x 4 KB); ws 0,2 add.
    // Phase B: ws 2 -> slot wt; ws 0 adds + stores.
    float2* area = (float2*)lds;
#pragma unroll
    for (int q = 0; q < 4; ++q) {
        const int d0 = 2 * q;
        auto writeP = [&](int slot) {
#pragma unroll
            for (int e = 0; e < 2; ++e)
#pragma unroll
                for (int r = 0; r < 4; ++r) {
                    const int row = hi * 4 + r;
                    area[slot * 512 + (e * 16 + row) * 16 + lm] =
                        (float2){acc[d0 + e][0][r], acc[d0 + e][1][r]};
                }
        };
        auto addP = [&](int slot) {
#pragma unroll
            for (int e = 0; e < 2; ++e)
#pragma unroll
                for (int r = 0; r < 4; ++r) {
                    const int row = hi * 4 + r;
                    float2 v = area[slot * 512 + (e * 16 + row) * 16 + lm];
                    acc[d0 + e][0][r] += v.x;
                    acc[d0 + e][1][r] += v.y;
                }
        };
        if (ws & 1) writeP(wt * 2 + (ws >> 1));
        __syncthreads();
        if (!(ws & 1)) addP(wt * 2 + (ws >> 1));
        __syncthreads();
        if (ws == 2) writeP(wt);
        __syncthreads();
        if (ws == 0) {
            addP(wt);
#pragma unroll
            for (int e = 0; e < 2; ++e) {
                const int d = (d0 + e) * 16 + lm;
#pragma unroll
                for (int r = 0; r < 4; ++r) {
                    const int tt = t0 + wt * 16 + hi * 4 + r;
                    *(float2*)&out[(((long)b * NTt + tt) * DZc + d) * NKc] =
                        (float2){acc[d0 + e][0][r], acc[d0 + e][1][r]};
                }
            }
        }
        __syncthreads();
    }
}

// ---------------------------------------------------------------------------
// Fallback (R1 kernel, known good) if ws is too small.
// ---------------------------------------------------------------------------
__global__ __launch_bounds__(256, 1)
void setconv_fused(const float* __restrict__ xgrid, const float* __restrict__ zgrid,
                   const float* __restrict__ xt, const float* __restrict__ lsp,
                   float* __restrict__ out)
{
    __shared__ __align__(16) short zt[2][DZc * 32];
    __shared__ __align__(16) float xgf[2][32 * 2];

    const int tid  = threadIdx.x;
    const int lane = tid & 63;
    const int wid  = tid >> 6;
    const int wt = wid >> 1;
    const int wd = wid & 1;
    const int hi = lane >> 4;
    const int lm = lane & 15;

    const int lb = ((blockIdx.x & 7) << 5) | (blockIdx.x >> 3);
    const int b  = lb >> 6;
    const int t0 = (lb & 63) << 6;

    float a00, a01, a10, a11;
    {
        const float LOG2E = 1.4426950408889634f;
        float cf[2][2];
#pragma unroll
        for (int d = 0; d < 2; ++d)
#pragma unroll
            for (int k = 0; k < 2; ++k) {
                float p  = lsp[d * 2 + k];
                float sp = fmaxf(p, 0.0f) + log1pf(__expf(-fabsf(p)));
                float ls = 1e-5f + sp;
                cf[d][k] = -0.5f * LOG2E / (ls * ls);
            }
        a00 = cf[0][0]; a01 = cf[0][1]; a10 = cf[1][0]; a11 = cf[1][1];
    }

    float xtx[2], xty[2];
#pragma unroll
    for (int ts = 0; ts < 2; ++ts) {
        int t = t0 + wt * 32 + ts * 16 + lm;
        const float* p = &xt[((long)b * NTt + t) * 2];
        xtx[ts] = p[0]; xty[ts] = p[1];
    }

    f32x4 acc[2][4][2];
#pragma unroll
    for (int ts = 0; ts < 2; ++ts)
#pragma unroll
        for (int db = 0; db < 4; ++db)
#pragma unroll
            for (int k = 0; k < 2; ++k)
                acc[ts][db][k] = (f32x4){0.f, 0.f, 0.f, 0.f};

    const int dcol = tid & 127;
    const int g8a  = tid >> 7;
    const long zbase = (long)b * NG * DZc;
    const int swz = (dcol >> 1) & 3;
    const int soff0 = dcol * 32 + ((g8a       ^ swz) * 8);
    const int soff1 = dcol * 32 + (((g8a + 2) ^ swz) * 8);

    float zv[16];
    float xgv = 0.f;

    auto stage_load = [&](int c) {
        const int g0 = c * 32;
        const float* zc0 = zgrid + zbase + (long)(g0 + g8a * 8) * DZc + dcol;
        const float* zc1 = zgrid + zbase + (long)(g0 + (g8a + 2) * 8) * DZc + dcol;
#pragma unroll
        for (int j = 0; j < 8; ++j) zv[j] = zc0[j * DZc];
#pragma unroll
        for (int j = 0; j < 8; ++j) zv[8 + j] = zc1[j * DZc];
        if (wid == 0) xgv = xgrid[((long)b * NG + g0) * 2 + tid];
    };

    auto stage_store = [&](int buf) {
        bf16x8 p0, p1;
#pragma unroll
        for (int j = 0; j < 8; ++j) { p0[j] = f2bf(zv[j]); p1[j] = f2bf(zv[8 + j]); }
        *(bf16x8*)&zt[buf][soff0] = p0;
        *(bf16x8*)&zt[buf][soff1] = p1;
        if (wid == 0) xgf[buf][tid] = xgv;
    };

    auto compute = [&](int buf) {
        typedef __attribute__((ext_vector_type(4))) short short4v;
        bf16x8 Bf[4];
#pragma unroll
        for (int db = 0; db < 4; ++db) {
            const int d = wd * 64 + db * 16 + lm;
            const short* zb = &zt[buf][d * 32];
            const int q = hi ^ (lm & 6);
            short4v lo = *(const short4v*)(zb + q * 4);
            short4v hh = *(const short4v*)(zb + (q ^ 4) * 4);
            Bf[db] = (bf16x8){lo.x, lo.y, lo.z, lo.w, hh.x, hh.y, hh.z, hh.w};
        }
        const float4* xp  = (const float4*)&xgf[buf][hi * 8];
        const float4* xp2 = (const float4*)&xgf[buf][32 + hi * 8];
        float4 x01 = xp[0],  x23 = xp[1];
        float4 x45 = xp2[0], x67 = xp2[1];
        float gx[8] = {x01.x, x01.z, x23.x, x23.z, x45.x, x45.z, x67.x, x67.z};
        float gy[8] = {x01.y, x01.w, x23.y, x23.w, x45.y, x45.w, x67.y, x67.w};
#pragma unroll
        for (int ts = 0; ts < 2; ++ts) {
            bf16x8 A0, A1;
#pragma unroll
            for (int j = 0; j < 8; ++j) {
                float dx = xtx[ts] - gx[j];
                float dy = xty[ts] - gy[j];
                float s0 = dx * dx, s1 = dy * dy;
                A0[j] = f2bf(__builtin_amdgcn_exp2f(s0 * a00 + s1 * a10));
                A1[j] = f2bf(__builtin_amdgcn_exp2f(s0 * a01 + s1 * a11));
            }
#pragma unroll
            for (int db = 0; db < 4; ++db) {
                acc[ts][db][0] = __builtin_amdgcn_mfma_f32_16x16x32_bf16(A0, Bf[db], acc[ts][db][0], 0, 0, 0);
                acc[ts][db][1] = __builtin_amdgcn_mfma_f32_16x16x32_bf16(A1, Bf[db], acc[ts][db][1], 0, 0, 0);
            }
        }
    };

    stage_load(0);
    stage_store(0);
    __syncthreads();

    for (int c = 0; c < NG / 32; ++c) {
        const int cur = c & 1;
        const int nxt = cur ^ 1;
        if (c + 1 < NG / 32) stage_load(c + 1);
        compute(cur);
        if (c + 1 < NG / 32) stage_store(nxt);
        __syncthreads();
    }

#pragma unroll
    for (int ts = 0; ts < 2; ++ts)
#pragma unroll
        for (int db = 0; db < 4; ++db) {
            const int d = wd * 64 + db * 16 + lm;
#pragma unroll
            for (int r = 0; r < 4; ++r) {
                const int t = t0 + wt * 32 + ts * 16 + hi * 4 + r;
                float2 v = {acc[ts][db][0][r], acc[ts][db][1][r]};
                *(float2*)&out[((long)(b * NTt + t) * DZc + d) * NKc] = v;
            }
        }
}

extern "C" void kernel_launch(void* const* d_in, const int* in_sizes, int n_in,
                              void* d_out, int out_size, void* d_ws, size_t ws_size,
                              hipStream_t stream) {
    const float* xg  = (const float*)d_in[0];   // x_grid [4,64,64,2]
    const float* zg  = (const float*)d_in[1];   // z_grid [4,64,64,128]
    const float* xtp = (const float*)d_in[2];   // xt     [4,4096,2]
    const float* ls  = (const float*)d_in[3];   // lengthscale_param [2,2]
    float* o = (float*)d_out;                   // [4,4096,256] fp32

    if (ws_size >= (size_t)IMG_BYTES) {
        short* img = (short*)d_ws;
        hipLaunchKernelGGL(zcvt_kernel, dim3(512), dim3(256), 0, stream, zg, img);
        hipLaunchKernelGGL(setconv_main, dim3(256), dim3(1024), 0, stream, xg, xtp, ls, img, o);
    } else {
        hipLaunchKernelGGL(setconv_fused, dim3(256), dim3(256), 0, stream, xg, zg, xtp, ls, o);
    }
}